// Round 2
// baseline (7224.313 us; speedup 1.0000x reference)
//
#include <hip/hip_runtime.h>
#include <hip/hip_bf16.h>

// DissipativeSimplestRINN: sequential RK4 + fixed-point tanh solves.
// 64 blocks x 256 threads; block = 16 batch rows for all T steps (rows independent).
// All GEMMs: swapped-operand mfma_f32_16x16x32_bf16 (weights as constant A-frags in regs).
// w exchanged via double-buffered XOR-swizzled LDS; x fp32 in regs with hi/lo bf16 split.

#define T_SZ 1024
#define NY 32
#define NX 16
#define NW 128
#define NU 8
#define DT_F 0.01f
#define NCOLD 30
#define NWARM 5

typedef __attribute__((ext_vector_type(8))) short bf8v;   // 8 bf16 (4 VGPR)
typedef __attribute__((ext_vector_type(4))) float f4v;    // MFMA C/D

#define MFMA16(a, b, c) __builtin_amdgcn_mfma_f32_16x16x32_bf16((a), (b), (c), 0, 0, 0)

__device__ __forceinline__ unsigned short f2bf(float f) {
  return __builtin_bit_cast(unsigned short, __float2bfloat16(f));
}
__device__ __forceinline__ float bf2f(unsigned short u) {
  return __bfloat162float(__builtin_bit_cast(__hip_bfloat16, u));
}
__device__ __forceinline__ float tanh_fast(float z) {
  // tanh(z) = 1 - 2/(exp(2z)+1); stable at +/-inf. v_exp_f32 + v_rcp_f32.
  float e = __builtin_amdgcn_exp2f(z * 2.8853900817779268f);  // 2*log2(e)
  return 1.0f - 2.0f * __builtin_amdgcn_rcpf(e + 1.0f);
}

__global__ __launch_bounds__(256, 1) void rinn_kernel(
    const float* __restrict__ obs, const float* __restrict__ x0,
    const float* __restrict__ A_T, const float* __restrict__ Bw_T,
    const float* __restrict__ By_T, const float* __restrict__ Cv_T,
    const float* __restrict__ Dvw_T, const float* __restrict__ Dvy_T,
    const float* __restrict__ Cu_T, const float* __restrict__ Duw_T,
    const float* __restrict__ Duy_T, const float* __restrict__ log_stds,
    float* __restrict__ out) {
  // w: 2 bufs x [16 rows][128 bf16], byte = buf*4096 + r*256 + (2k ^ ((r&7)<<4))
  __shared__ __align__(16) char wlds[8192];
  // x: 2 bufs x [16 rows][32 bf16] = [hi(16) | lo(16)]
  __shared__ __align__(16) char xlds[2048];

  const int tid = (int)threadIdx.x;
  const int wv = tid >> 6;          // wave 0..3
  const int lane = tid & 63;
  const int r = lane & 15;          // batch-col inside group / A-row index
  const int h = lane >> 4;          // lane quadrant
  const long grow = (long)(blockIdx.x * 16 + r);
  const int sw = (r & 7) << 4;      // LDS XOR swizzle (bank spread)

  // ---- constant A-fragments (weights live in registers forever) ----
  // Solve GEMM: out^T[j][row] = sum_k Dvw_T[k][j] * w[row][k]
  bf8v Adw[2][4], Ady[2], Acv[2];
#pragma unroll
  for (int gi = 0; gi < 2; ++gi) {
    const int j = 16 * (2 * wv + gi) + r;
#pragma unroll
    for (int f = 0; f < 4; ++f)
#pragma unroll
      for (int q = 0; q < 8; ++q)
        Adw[gi][f][q] = (short)f2bf(Dvw_T[(32 * f + 8 * h + q) * NW + j]);
#pragma unroll
    for (int q = 0; q < 8; ++q) {
      Ady[gi][q] = (short)f2bf(Dvy_T[(8 * h + q) * NW + j]);        // used twice (y hi/lo)
      Acv[gi][q] = (short)f2bf(Cv_T[((8 * h + q) & 15) * NW + j]);  // k&15: x hi/lo repeat
    }
  }
  // wave0: xdot frags (A_T pad, Bw_T, By_T); wave1: u frags (Cu/Duw/Duy, rows>=8 zero)
  bf8v Ax16, Ak[4], Ay32;
  {
    const bool is0 = (wv == 0), is1 = (wv == 1);
#pragma unroll
    for (int q = 0; q < 8; ++q) {
      int k = 8 * h + q;
      float vx = 0.f, vy = 0.f;
      if (is0)              { vx = A_T[(k & 15) * NX + r];  vy = By_T[k * NX + r]; }
      else if (is1 && r < NU){ vx = Cu_T[(k & 15) * NU + r]; vy = Duy_T[k * NU + r]; }
      Ax16[q] = (short)f2bf(vx);
      Ay32[q] = (short)f2bf(vy);
    }
#pragma unroll
    for (int f = 0; f < 4; ++f)
#pragma unroll
      for (int q = 0; q < 8; ++q) {
        int k = 32 * f + 8 * h + q;
        float v = 0.f;
        if (is0)               v = Bw_T[k * NX + r];
        else if (is1 && r < NU) v = Duw_T[k * NU + r];
        Ak[f][q] = (short)f2bf(v);
      }
  }
  f4v lsv;
#pragma unroll
  for (int i = 0; i < 4; ++i) lsv[i] = (h >= 2) ? log_stds[4 * (h - 2) + i] : 0.f;

  // ---- state init ----
  f4v xr = {0.f, 0.f, 0.f, 0.f};  // wave0: x[4h+i][grow] fp32 master
  if (wv == 0) {
#pragma unroll
    for (int i = 0; i < 4; ++i) xr[i] = x0[grow * NX + 4 * h + i];
  }

  auto write_x = [&](int buf, f4v v) {  // hi/lo bf16 split into xlds
    unsigned short b0 = f2bf(v[0]), b1 = f2bf(v[1]), b2 = f2bf(v[2]), b3 = f2bf(v[3]);
    uint2 hp, lp;
    hp.x = (unsigned)b0 | ((unsigned)b1 << 16);
    hp.y = (unsigned)b2 | ((unsigned)b3 << 16);
    lp.x = (unsigned)f2bf(v[0] - bf2f(b0)) | ((unsigned)f2bf(v[1] - bf2f(b1)) << 16);
    lp.y = (unsigned)f2bf(v[2] - bf2f(b2)) | ((unsigned)f2bf(v[3] - bf2f(b3)) << 16);
    char* base = xlds + buf * 1024 + r * 64;
    *(uint2*)(base + 8 * h) = hp;
    *(uint2*)(base + 32 + 8 * h) = lp;
  };

  {  // zero w buf0 (cold-start w0), stage x0
    uint4 z; z.x = z.y = z.z = z.w = 0u;
    ((uint4*)wlds)[tid] = z;  // 256*16B = 4KB = buf0
    if (wv == 0) write_x(0, xr);
  }
  __syncthreads();

  // y fragments (hi/lo) for t=0
  const float* orow = obs + grow * T_SZ * NY;
  bf8v By0, By1;
  {
    float yf[8];
#pragma unroll
    for (int q = 0; q < 8; ++q) yf[q] = orow[8 * h + q];
#pragma unroll
    for (int q = 0; q < 8; ++q) {
      unsigned short hi = f2bf(yf[q]);
      By0[q] = (short)hi;
      By1[q] = (short)f2bf(yf[q] - bf2f(hi));
    }
  }

  int cur = 0;  // live w buffer
  f4v cb[2], cbias[2];

  auto do_solve = [&](int n) {
    for (int it = 0; it < n; ++it) {
      bf8v bw[4];
#pragma unroll
      for (int f = 0; f < 4; ++f)
        bw[f] = *(const bf8v*)(wlds + cur * 4096 + r * 256 + ((64 * f + 16 * h) ^ sw));
#pragma unroll
      for (int gi = 0; gi < 2; ++gi) {
        f4v c = cbias[gi];
#pragma unroll
        for (int f = 0; f < 4; ++f) c = MFMA16(Adw[gi][f], bw[f], c);
        uint2 pk;
        pk.x = (unsigned)f2bf(tanh_fast(c[0])) | ((unsigned)f2bf(tanh_fast(c[1])) << 16);
        pk.y = (unsigned)f2bf(tanh_fast(c[2])) | ((unsigned)f2bf(tanh_fast(c[3])) << 16);
        *(uint2*)(wlds + (cur ^ 1) * 4096 + r * 256 + ((32 * (2 * wv + gi) + 8 * h) ^ sw)) = pk;
      }
      __syncthreads();
      cur ^= 1;
    }
  };

  auto stage_bias = [&](int xbuf) {  // cbias = y_bias + xs@Cv (x hi/lo via k&15 repeat)
    bf8v bx = *(const bf8v*)(xlds + xbuf * 1024 + r * 64 + 16 * h);
#pragma unroll
    for (int gi = 0; gi < 2; ++gi) cbias[gi] = MFMA16(Acv[gi], bx, cb[gi]);
  };

  auto kchain = [&](int xbuf) -> f4v {  // xdot (wave0) / u (wave1)
    bf8v bw[4];
#pragma unroll
    for (int f = 0; f < 4; ++f)
      bw[f] = *(const bf8v*)(wlds + cur * 4096 + r * 256 + ((64 * f + 16 * h) ^ sw));
    bf8v bx = *(const bf8v*)(xlds + xbuf * 1024 + r * 64 + 16 * h);
    f4v c = {0.f, 0.f, 0.f, 0.f};
    c = MFMA16(Ax16, bx, c);
#pragma unroll
    for (int f = 0; f < 4; ++f) c = MFMA16(Ak[f], bw[f], c);
    c = MFMA16(Ay32, By0, c);
    c = MFMA16(Ay32, By1, c);
    return c;
  };

  f4v acc = {0.f, 0.f, 0.f, 0.f};
  for (int t = 0; t < T_SZ; ++t) {
    // y-bias (computed once per step; A reused for hi and lo B)
#pragma unroll
    for (int gi = 0; gi < 2; ++gi) {
      f4v c = {0.f, 0.f, 0.f, 0.f};
      c = MFMA16(Ady[gi], By0, c);
      c = MFMA16(Ady[gi], By1, c);
      cb[gi] = c;
    }
    // prefetch next y (latency hidden under the step)
    float yn[8];
    {
      const long tn = (t + 1 < T_SZ) ? (t + 1) : t;
#pragma unroll
      for (int q = 0; q < 8; ++q) yn[q] = orow[tn * NY + 8 * h + q];
    }

    // ---- stage 1: wk solve (cold 30 at t=0), k1, u-output ----
    stage_bias(0);
    do_solve(t == 0 ? NCOLD : NWARM);
    f4v kv = {0.f, 0.f, 0.f, 0.f};
    if (wv < 2) kv = kchain(0);
    if (wv == 1) {
      f4v sv;
#pragma unroll
      for (int i = 0; i < 4; ++i) sv[i] = (h < 2) ? kv[i] : lsv[i];
      *(f4v*)(out + (grow * T_SZ + t) * 16 + 4 * h) = sv;  // [u | log_stds]
    }
    f4v xs;
    if (wv == 0) {
      acc = kv;
#pragma unroll
      for (int i = 0; i < 4; ++i) xs[i] = xr[i] + (0.5f * DT_F) * kv[i];
      write_x(1, xs);
    }
    __syncthreads();

    // ---- stage 2 ----
    stage_bias(1);
    do_solve(NWARM);
    if (wv == 0) {
      kv = kchain(1);
#pragma unroll
      for (int i = 0; i < 4; ++i) { acc[i] += 2.f * kv[i]; xs[i] = xr[i] + (0.5f * DT_F) * kv[i]; }
      write_x(0, xs);
    }
    __syncthreads();

    // ---- stage 3 ----
    stage_bias(0);
    do_solve(NWARM);
    if (wv == 0) {
      kv = kchain(0);
#pragma unroll
      for (int i = 0; i < 4; ++i) { acc[i] += 2.f * kv[i]; xs[i] = xr[i] + DT_F * kv[i]; }
      write_x(1, xs);
    }
    __syncthreads();

    // ---- stage 4: w4 stays in wlds[cur] as next step's warm start ----
    stage_bias(1);
    do_solve(NWARM);
    if (wv == 0) {
      kv = kchain(1);
#pragma unroll
      for (int i = 0; i < 4; ++i) xr[i] += (DT_F / 6.f) * (acc[i] + kv[i]);
      write_x(0, xr);  // x_next -> stage-1 buffer of next step
    }
    // swap in prefetched y
#pragma unroll
    for (int q = 0; q < 8; ++q) {
      unsigned short hi = f2bf(yn[q]);
      By0[q] = (short)hi;
      By1[q] = (short)f2bf(yn[q] - bf2f(hi));
    }
    __syncthreads();
  }
}

extern "C" void kernel_launch(void* const* d_in, const int* in_sizes, int n_in,
                              void* d_out, int out_size, void* d_ws, size_t ws_size,
                              hipStream_t stream) {
  (void)in_sizes; (void)n_in; (void)out_size; (void)d_ws; (void)ws_size;
  rinn_kernel<<<64, 256, 0, stream>>>(
      (const float*)d_in[0], (const float*)d_in[1], (const float*)d_in[2],
      (const float*)d_in[3], (const float*)d_in[4], (const float*)d_in[5],
      (const float*)d_in[6], (const float*)d_in[7], (const float*)d_in[8],
      (const float*)d_in[9], (const float*)d_in[10], (const float*)d_in[11],
      (float*)d_out);
}

// Round 3
// 6200.397 us; speedup vs baseline: 1.1651x; 1.1651x over previous
//
#include <hip/hip_runtime.h>
#include <hip/hip_bf16.h>

// DissipativeSimplestRINN: sequential RK4 + fixed-point tanh solves.
// 64 blocks x 256 threads; block = 16 batch rows; 4 waves split the 128 w-columns.
// j-remap j(wv,gi,h,i)=32wv+8h+4gi+i => lane's outputs are 16B-contiguous (1 b128 write)
// and wave's own slice == B-frag slot 0 (kept in regs, no LDS round-trip).
// Barriers: exactly 1 per solve iteration. x replicated in all waves (redundant xdot).

#define T_SZ 1024
#define NY 32
#define NX 16
#define NW 128
#define NU 8
#define DT_F 0.01f
#define NCOLD 30
#define NWARM 5
#define KAPPA 2.8853900817779268f  // 2*log2(e): prescale solve weights so tanh needs no mul

typedef __attribute__((ext_vector_type(8))) short bf8v;   // 8 bf16 (4 VGPR)
typedef __attribute__((ext_vector_type(4))) float f4v;    // MFMA C/D

#define MFMA16(a, b, c) __builtin_amdgcn_mfma_f32_16x16x32_bf16((a), (b), (c), 0, 0, 0)

__device__ __forceinline__ unsigned short f2bf(float f) {
  return __builtin_bit_cast(unsigned short, __float2bfloat16(f));
}
__device__ __forceinline__ float bf2f(unsigned short u) {
  return __bfloat162float(__builtin_bit_cast(__hip_bfloat16, u));
}
__device__ __forceinline__ short tanh_bf(float z) {  // z pre-scaled by KAPPA
  float e = __builtin_amdgcn_exp2f(z);
  float r = __builtin_amdgcn_rcpf(e + 1.0f);
  return (short)f2bf(1.0f - 2.0f * r);
}

__global__ __launch_bounds__(256, 1) void rinn_kernel(
    const float* __restrict__ obs, const float* __restrict__ x0,
    const float* __restrict__ A_T, const float* __restrict__ Bw_T,
    const float* __restrict__ By_T, const float* __restrict__ Cv_T,
    const float* __restrict__ Dvw_T, const float* __restrict__ Dvy_T,
    const float* __restrict__ Cu_T, const float* __restrict__ Duw_T,
    const float* __restrict__ Duy_T, const float* __restrict__ log_stds,
    float* __restrict__ out) {
  // w: 2 bufs x [16 rows][128 bf16]; byte = buf*4096 + r*256 + ((2j) ^ ((r&7)<<4))
  __shared__ __align__(16) char wlds[8192];
  // x: per-wave private [16 rows][32 bf16] = [hi(16)|lo(16)]  (no barrier needed)
  __shared__ __align__(16) char xlds[4096];

  const int tid = (int)threadIdx.x;
  const int wv = tid >> 6;
  const int lane = tid & 63;
  const int r = lane & 15;
  const int h = lane >> 4;
  const long grow = (long)(blockIdx.x * 16 + r);
  const int sw = (r & 7) << 4;
  const int rbase = r * 256;

  // LDS 16B-slot offsets per B-frag slot s (slot s holds K-block f=(wv+s)&3).
  const int ro0 = (64 * wv + 16 * h) ^ sw;               // own slot == write offset
  const int ro1 = (64 * ((wv + 1) & 3) + 16 * h) ^ sw;
  const int ro2 = (64 * ((wv + 2) & 3) + 16 * h) ^ sw;
  const int ro3 = (64 * ((wv + 3) & 3) + 16 * h) ^ sw;

  // ---- constant A-fragments ----
  // Output j for (gi, C-row m=4h'+i): j = 32wv + 8h' + 4gi + i.
  bf8v Adw[2][4], Acv[2], Ady[2];
#pragma unroll
  for (int gi = 0; gi < 2; ++gi) {
    const int j = 32 * wv + 8 * (r >> 2) + 4 * gi + (r & 3);  // A-row r -> output j
#pragma unroll
    for (int s = 0; s < 4; ++s) {
      const int f = (wv + s) & 3;
#pragma unroll
      for (int q = 0; q < 8; ++q)
        Adw[gi][s][q] = (short)f2bf(KAPPA * Dvw_T[(32 * f + 8 * h + q) * NW + j]);
    }
#pragma unroll
    for (int q = 0; q < 8; ++q) {
      Acv[gi][q] = (short)f2bf(KAPPA * Cv_T[((8 * h + q) & 15) * NW + j]);  // x hi/lo
      Ady[gi][q] = (short)f2bf(KAPPA * Dvy_T[(8 * h + q) * NW + j]);
    }
  }
  // xdot frags (ALL waves, redundant) + u frags (wave1 only; zero elsewhere)
  bf8v Ax, Akx[4], Ayx, Au, Aku[4], Ayu;
#pragma unroll
  for (int q = 0; q < 8; ++q) {
    int k = 8 * h + q;
    Ax[q] = (short)f2bf(A_T[(k & 15) * NX + r]);
    Ayx[q] = (short)f2bf(By_T[k * NX + r]);
    float cu = 0.f, dy = 0.f;
    if (wv == 1 && r < NU) { cu = Cu_T[(k & 15) * NU + r]; dy = Duy_T[k * NU + r]; }
    Au[q] = (short)f2bf(cu);
    Ayu[q] = (short)f2bf(dy);
  }
#pragma unroll
  for (int s = 0; s < 4; ++s) {
    const int f = (wv + s) & 3;
#pragma unroll
    for (int q = 0; q < 8; ++q) {
      int k = 32 * f + 8 * h + q;
      Akx[s][q] = (short)f2bf(Bw_T[k * NX + r]);
      float du = 0.f;
      if (wv == 1 && r < NU) du = Duw_T[k * NU + r];
      Aku[s][q] = (short)f2bf(du);
    }
  }
  f4v lsv;
#pragma unroll
  for (int i = 0; i < 4; ++i) lsv[i] = (h >= 2) ? log_stds[4 * (h - 2) + i] : 0.f;

  f4v xr;
#pragma unroll
  for (int i = 0; i < 4; ++i) xr[i] = x0[grow * NX + 4 * h + i];

  char* xbase = xlds + wv * 1024;
  auto write_x = [&](f4v v) {  // hi/lo bf16 split, per-wave private
    unsigned short b0 = f2bf(v[0]), b1 = f2bf(v[1]), b2 = f2bf(v[2]), b3 = f2bf(v[3]);
    uint2 hp, lp;
    hp.x = (unsigned)b0 | ((unsigned)b1 << 16);
    hp.y = (unsigned)b2 | ((unsigned)b3 << 16);
    lp.x = (unsigned)f2bf(v[0] - bf2f(b0)) | ((unsigned)f2bf(v[1] - bf2f(b1)) << 16);
    lp.y = (unsigned)f2bf(v[2] - bf2f(b2)) | ((unsigned)f2bf(v[3] - bf2f(b3)) << 16);
    *(uint2*)(xbase + r * 64 + 8 * h) = hp;
    *(uint2*)(xbase + r * 64 + 32 + 8 * h) = lp;
  };
  auto read_bx = [&]() { return *(const bf8v*)(xbase + r * 64 + 16 * h); };

  {  // zero w buf0 (cold-start w0); stage x0
    uint4 z; z.x = z.y = z.z = z.w = 0u;
    ((uint4*)wlds)[tid] = z;
    write_x(xr);
  }
  __syncthreads();

  const float* orow = obs + grow * T_SZ * NY;
  bf8v By0, By1;
  {
    float yf[8];
#pragma unroll
    for (int q = 0; q < 8; ++q) yf[q] = orow[8 * h + q];
#pragma unroll
    for (int q = 0; q < 8; ++q) {
      unsigned short hi = f2bf(yf[q]);
      By0[q] = (short)hi;
      By1[q] = (short)f2bf(yf[q] - bf2f(hi));
    }
  }

  int co = 0;                 // live w buffer byte offset (0 / 4096)
  bf8v of8 = {};              // own-slice packed outputs (== B-frag slot 0); w0 = 0
  f4v cbias0, cbias1;

  auto solve_iter = [&]() {
    const char* wb = wlds + co;
    bf8v b1 = *(const bf8v*)(wb + rbase + ro1);
    bf8v b2 = *(const bf8v*)(wb + rbase + ro2);
    bf8v b3 = *(const bf8v*)(wb + rbase + ro3);
    f4v c0 = MFMA16(Adw[0][0], of8, cbias0);   // own slot first: hides LDS latency
    f4v c1 = MFMA16(Adw[1][0], of8, cbias1);
    c0 = MFMA16(Adw[0][1], b1, c0);  c1 = MFMA16(Adw[1][1], b1, c1);
    c0 = MFMA16(Adw[0][2], b2, c0);  c1 = MFMA16(Adw[1][2], b2, c1);
    c0 = MFMA16(Adw[0][3], b3, c0);  c1 = MFMA16(Adw[1][3], b3, c1);
    bf8v o;
    o[0] = tanh_bf(c0[0]); o[1] = tanh_bf(c0[1]); o[2] = tanh_bf(c0[2]); o[3] = tanh_bf(c0[3]);
    o[4] = tanh_bf(c1[0]); o[5] = tanh_bf(c1[1]); o[6] = tanh_bf(c1[2]); o[7] = tanh_bf(c1[3]);
    of8 = o;
    *(bf8v*)(wlds + (co ^ 4096) + rbase + ro0) = o;   // single contiguous b128 write
    __syncthreads();
    co ^= 4096;
  };

  auto kchain = [&](bf8v bx, int t, bool do_u) -> f4v {  // xdot (all waves) / u (wave1)
    const char* wb = wlds + co;
    bf8v b1 = *(const bf8v*)(wb + rbase + ro1);
    bf8v b2 = *(const bf8v*)(wb + rbase + ro2);
    bf8v b3 = *(const bf8v*)(wb + rbase + ro3);
    f4v z = {0.f, 0.f, 0.f, 0.f};
    f4v c = MFMA16(Ax, bx, z);
    c = MFMA16(Akx[0], of8, c);
    c = MFMA16(Akx[1], b1, c); c = MFMA16(Akx[2], b2, c); c = MFMA16(Akx[3], b3, c);
    c = MFMA16(Ayx, By0, c);   c = MFMA16(Ayx, By1, c);
    if (do_u && wv == 1) {
      f4v cu = MFMA16(Au, bx, z);
      cu = MFMA16(Aku[0], of8, cu);
      cu = MFMA16(Aku[1], b1, cu); cu = MFMA16(Aku[2], b2, cu); cu = MFMA16(Aku[3], b3, cu);
      cu = MFMA16(Ayu, By0, cu);   cu = MFMA16(Ayu, By1, cu);
      f4v sv;
#pragma unroll
      for (int i = 0; i < 4; ++i) sv[i] = (h < 2) ? cu[i] : lsv[i];
      *(f4v*)(out + (grow * T_SZ + t) * 16 + 4 * h) = sv;
    }
    return c;
  };

  for (int t = 0; t < T_SZ; ++t) {
    f4v zz = {0.f, 0.f, 0.f, 0.f};
    f4v cb0 = MFMA16(Ady[0], By0, zz); cb0 = MFMA16(Ady[0], By1, cb0);
    f4v cb1 = MFMA16(Ady[1], By0, zz); cb1 = MFMA16(Ady[1], By1, cb1);

    // ---- stage 1 ----
    bf8v bx = read_bx();
    cbias0 = MFMA16(Acv[0], bx, cb0); cbias1 = MFMA16(Acv[1], bx, cb1);
    const int n1 = (t == 0) ? NCOLD : NWARM;
    for (int it = 0; it < n1; ++it) solve_iter();
    // prefetch next y here (loads drain at stage-2's first barrier, mostly hidden)
    float yn[8];
    {
      const long tn = (t + 1 < T_SZ) ? (t + 1) : t;
#pragma unroll
      for (int q = 0; q < 8; ++q) yn[q] = orow[tn * NY + 8 * h + q];
    }
    f4v kv = kchain(bx, t, true);
    f4v acc = kv, xs;
#pragma unroll
    for (int i = 0; i < 4; ++i) xs[i] = xr[i] + (0.5f * DT_F) * kv[i];
    write_x(xs);

    // ---- stage 2 ----
    bx = read_bx();
    cbias0 = MFMA16(Acv[0], bx, cb0); cbias1 = MFMA16(Acv[1], bx, cb1);
    for (int it = 0; it < NWARM; ++it) solve_iter();
    kv = kchain(bx, t, false);
#pragma unroll
    for (int i = 0; i < 4; ++i) { acc[i] += 2.f * kv[i]; xs[i] = xr[i] + (0.5f * DT_F) * kv[i]; }
    write_x(xs);

    // ---- stage 3 ----
    bx = read_bx();
    cbias0 = MFMA16(Acv[0], bx, cb0); cbias1 = MFMA16(Acv[1], bx, cb1);
    for (int it = 0; it < NWARM; ++it) solve_iter();
    kv = kchain(bx, t, false);
#pragma unroll
    for (int i = 0; i < 4; ++i) { acc[i] += 2.f * kv[i]; xs[i] = xr[i] + DT_F * kv[i]; }
    write_x(xs);

    // ---- stage 4 ----
    bx = read_bx();
    cbias0 = MFMA16(Acv[0], bx, cb0); cbias1 = MFMA16(Acv[1], bx, cb1);
    for (int it = 0; it < NWARM; ++it) solve_iter();
    kv = kchain(bx, t, false);
#pragma unroll
    for (int i = 0; i < 4; ++i) xr[i] += (DT_F / 6.f) * (acc[i] + kv[i]);
    write_x(xr);

    // swap in prefetched y
#pragma unroll
    for (int q = 0; q < 8; ++q) {
      unsigned short hi = f2bf(yn[q]);
      By0[q] = (short)hi;
      By1[q] = (short)f2bf(yn[q] - bf2f(hi));
    }
  }
}

extern "C" void kernel_launch(void* const* d_in, const int* in_sizes, int n_in,
                              void* d_out, int out_size, void* d_ws, size_t ws_size,
                              hipStream_t stream) {
  (void)in_sizes; (void)n_in; (void)out_size; (void)d_ws; (void)ws_size;
  rinn_kernel<<<64, 256, 0, stream>>>(
      (const float*)d_in[0], (const float*)d_in[1], (const float*)d_in[2],
      (const float*)d_in[3], (const float*)d_in[4], (const float*)d_in[5],
      (const float*)d_in[6], (const float*)d_in[7], (const float*)d_in[8],
      (const float*)d_in[9], (const float*)d_in[10], (const float*)d_in[11],
      (float*)d_out);
}